// Round 11
// baseline (99.961 us; speedup 1.0000x reference)
//
#include <hip/hip_runtime.h>
#include <math.h>

#define NPTS  4096
#define BATCH 2
#define KNB   20
#define WGRID 64
#define GCELLS (WGRID * WGRID)
#define NROUNDS 32
#define KBUF  192
#define KQ    16                            // queries per kNN block (1 wave each)
#define NEDGE (BATCH * NPTS * KNB)          // 163840
#define NPACK (NEDGE / 16)                  // 10240 u32 (2-bit codes)

// ---------------------------------------------------------------- kNN ----
// R4-proven shape (~38us): 16 waves/block, 1 query/wave, batch staged once
// in LDS (w = |p|^2 computed during staging). Two-pass distance (no d[64]
// array) => VGPR <= 64 => 8 waves/SIMD, 2 blocks/CU (LDS 70KB) => 32
// waves/CU. Threshold rank-select via ballot radix-select (R9, zero
// DS-pipe traffic, exact same value as bitonic sorted[19]).
__device__ __forceinline__ float knn_dist(const float4 c, const float px,
                                          const float py, const float pz,
                                          const float sqn, const int m,
                                          const int n) {
    const float dot = px * c.x + py * c.y + pz * c.z;
    float dist = (sqn + c.w) - 2.0f * dot;
    if (m == n) dist = -1.0f;
    return dist;
}

__device__ __forceinline__ unsigned long long knn_key(const float dist, const int m) {
    unsigned u = __float_as_uint(dist);
    u = (dist < 0.0f) ? ~u : (u | 0x80000000u);
    return ((unsigned long long)u << 32) | (unsigned)m;
}

__global__ __launch_bounds__(1024, 8) void knn_kernel(const float* __restrict__ pts,
                                                      int* __restrict__ idx) {
    const int tid  = threadIdx.x;
    const int lane = tid & 63;
    const int wid  = tid >> 6;                      // 0..15
    const int q    = blockIdx.x * KQ + wid;         // 0 .. B*N-1
    const int b    = q >> 12;
    const int n    = q & (NPTS - 1);
    const float* P = pts + (size_t)b * NPTS * 3;

    __shared__ float4 spts[NPTS];                       // 64 KB
    __shared__ unsigned short buf[KQ][KBUF];            //  6 KB

    for (int i = tid; i < NPTS; i += 1024) {
        const float x = P[i * 3 + 0], y = P[i * 3 + 1], z = P[i * 3 + 2];
        spts[i] = make_float4(x, y, z, x * x + y * y + z * z);
    }
    __syncthreads();

    const float4 me = spts[n];
    const float px = me.x, py = me.y, pz = me.z, sqn = me.w;

    // ---- pass 1: per-lane min over its 64 points (no storage)
    float lmin = 3e38f;
#pragma unroll
    for (int step = 0; step < 64; ++step) {
        const int m = lane + step * 64;
        lmin = fminf(lmin, knn_dist(spts[m], px, py, pz, sqn, m, n));
    }

    // ---- threshold = 20th smallest of the 64 lane-mins, via ballot
    // radix-select on the monotone uint mapping (no shuffles; exact
    // same value as bitonic sorted[19], duplicates included).
    unsigned ub = __float_as_uint(lmin);
    ub = (lmin < 0.0f) ? ~ub : (ub | 0x80000000u);
    unsigned val = 0;
    int need = KNB;                  // 20 => 0-indexed rank 19
    bool alive = true;
#pragma unroll
    for (int bit = 31; bit >= 0; --bit) {
        const unsigned bm = 1u << bit;
        const unsigned long long z = __ballot(alive && !(ub & bm));
        const int c = __popcll(z);
        const bool pick1 = (c < need);
        if (pick1) { need -= c; val |= bm; }
        alive = alive && (((ub & bm) != 0) == pick1);
    }
    float tsel;
    if (val & 0x80000000u) tsel = __uint_as_float(val & 0x7fffffffu);
    else                   tsel = __uint_as_float(~val);
    float thr = tsel + fabsf(tsel) * 1e-4f + 1e-6f;

    // ---- pass 2: recompute distances, compact candidate indices (u16)
    unsigned short* wbuf = buf[wid];
    int cnt = 0;
#pragma unroll
    for (int step = 0; step < 64; ++step) {
        const int m = lane + step * 64;
        const float dist = knn_dist(spts[m], px, py, pz, sqn, m, n);
        const bool keep = (dist <= thr);
        const unsigned long long mask = __ballot(keep);
        if (keep) {
            const int pos = cnt + __popcll(mask & ((1ull << lane) - 1ull));
            if (pos < KBUF) wbuf[pos] = (unsigned short)m;
        }
        cnt += __popcll(mask);
    }

    const int M = (cnt < KBUF) ? cnt : KBUF;
    int* op = idx + (size_t)q * KNB;
    const unsigned long long MAXK = ~0ull;
    if (M <= 64) {
        unsigned long long key = MAXK;
        if (lane < M) {
            const int m = (int)wbuf[lane];
            key = knn_key(knn_dist(spts[m], px, py, pz, sqn, m, n), m);
        }
#pragma unroll
        for (int k = 2; k <= 64; k <<= 1) {
#pragma unroll
            for (int j = k >> 1; j >= 1; j >>= 1) {
                const unsigned long long o = __shfl_xor(key, j, 64);
                const bool up    = ((lane & k) == 0);
                const bool lower = ((lane & j) == 0);
                const bool takeMin = (lower == up);
                const unsigned long long mn = key < o ? key : o;
                const unsigned long long mx = key < o ? o : key;
                key = takeMin ? mn : mx;
            }
        }
        if (lane < KNB) op[lane] = (int)(unsigned)(key & 0xffffffffu);
    } else {
        unsigned long long s0 = MAXK, s1 = MAXK, s2 = MAXK;
        if (lane < M) {
            const int m = (int)wbuf[lane];
            s0 = knn_key(knn_dist(spts[m], px, py, pz, sqn, m, n), m);
        }
        if (lane + 64 < M) {
            const int m = (int)wbuf[lane + 64];
            s1 = knn_key(knn_dist(spts[m], px, py, pz, sqn, m, n), m);
        }
        if (lane + 128 < M) {
            const int m = (int)wbuf[lane + 128];
            s2 = knn_key(knn_dist(spts[m], px, py, pz, sqn, m, n), m);
        }
#pragma unroll 1
        for (int r = 0; r < KNB; ++r) {
            unsigned long long kk = s0 < s1 ? s0 : s1;
            kk = kk < s2 ? kk : s2;
#pragma unroll
            for (int off = 32; off; off >>= 1) {
                const unsigned long long ok = __shfl_xor(kk, off, 64);
                kk = ok < kk ? ok : kk;
            }
            if (s0 == kk) s0 = MAXK;
            else if (s1 == kk) s1 = MAXK;
            else if (s2 == kk) s2 = MAXK;
            if (lane == 0) op[r] = (int)(unsigned)(kk & 0xffffffffu);
        }
    }
}

// ------------------------------------------------------- frames (eigh) ----
template <int p, int q, int r>
__device__ __forceinline__ void jrot(double A[3][3], double V[3][3]) {
    double apq = A[p][q];
    if (fabs(apq) < 1e-300) return;
    double app = A[p][p], aqq = A[q][q];
    double tau = (aqq - app) / (2.0 * apq);
    double sq  = sqrt(1.0 + tau * tau);
    double t   = (tau >= 0.0) ? (1.0 / (tau + sq)) : (1.0 / (tau - sq));
    double c   = 1.0 / sqrt(1.0 + t * t);
    double s   = t * c;
    A[p][p] = app - t * apq; A[q][q] = aqq + t * apq;
    A[p][q] = 0.0; A[q][p] = 0.0;
    double arp = A[r][p], arq = A[r][q];
    A[r][p] = c * arp - s * arq; A[p][r] = A[r][p];
    A[r][q] = s * arp + c * arq; A[q][r] = A[r][q];
#pragma unroll
    for (int i = 0; i < 3; ++i) {
        double vip = V[i][p], viq = V[i][q];
        V[i][p] = c * vip - s * viq;
        V[i][q] = s * vip + c * viq;
    }
}

__device__ __forceinline__ double selV(const double V[3][3], int i, int c) {
    return c == 0 ? V[i][0] : (c == 1 ? V[i][1] : V[i][2]);
}

// R10: neighbor coords loaded ONCE into registers (60 floats) instead of
// two scattered-load passes (120 -> 60 global loads). frames runs at
// <=1 wave/SIMD (128 waves total) with zero TLP, so the second pass's
// L2 latency (~200cy x 60 loads, 48KB > 32KB L1) was fully exposed.
// Arithmetic order unchanged => bit-identical output.
__global__ __launch_bounds__(64) void frames_kernel(const float* __restrict__ pts,
                                                    const int* __restrict__ idx,
                                                    float* __restrict__ frames,
                                                    float* __restrict__ normals) {
    const int g = blockIdx.x * 64 + threadIdx.x;    // 0 .. B*N-1
    const int b = g / NPTS;
    const float* P  = pts + (size_t)b * NPTS * 3;
    const int*   ip = idx + (size_t)g * KNB;

    float nx[KNB], ny[KNB], nz[KNB];
    float mx = 0.f, my = 0.f, mz = 0.f;
#pragma unroll
    for (int k = 0; k < KNB; ++k) {
        const int j = ip[k];
        nx[k] = P[j * 3 + 0]; ny[k] = P[j * 3 + 1]; nz[k] = P[j * 3 + 2];
        mx += nx[k]; my += ny[k]; mz += nz[k];
    }
    mx /= 20.0f; my /= 20.0f; mz /= 20.0f;

    float c00 = 0.f, c01 = 0.f, c02 = 0.f, c11 = 0.f, c12 = 0.f, c22 = 0.f;
#pragma unroll
    for (int k = 0; k < KNB; ++k) {
        const float x = nx[k] - mx;
        const float y = ny[k] - my;
        const float z = nz[k] - mz;
        c00 += x * x; c01 += x * y; c02 += x * z;
        c11 += y * y; c12 += y * z; c22 += z * z;
    }
    c00 *= 0.5f; c01 *= 0.5f; c02 *= 0.5f; c11 *= 0.5f; c12 *= 0.5f; c22 *= 0.5f;

    double A[3][3] = {{c00, c01, c02}, {c01, c11, c12}, {c02, c12, c22}};
    double V[3][3] = {{1, 0, 0}, {0, 1, 0}, {0, 0, 1}};
#pragma unroll
    for (int sw = 0; sw < 10; ++sw) {
        jrot<0, 1, 2>(A, V);
        jrot<0, 2, 1>(A, V);
        jrot<1, 2, 0>(A, V);
    }
    double e0 = A[0][0], e1 = A[1][1], e2 = A[2][2];
    int o0 = 0, o1 = 1, o2 = 2;
    if (e0 > e1) { double t = e0; e0 = e1; e1 = t; int o = o0; o0 = o1; o1 = o; }
    if (e1 > e2) { double t = e1; e1 = e2; e2 = t; int o = o1; o1 = o2; o2 = o; }
    if (e0 > e1) { double t = e0; e0 = e1; e1 = t; int o = o0; o0 = o1; o1 = o; }

    float* F = frames + (size_t)g * 9;
    F[0] = (float)selV(V, 0, o0); F[1] = (float)selV(V, 1, o0); F[2] = (float)selV(V, 2, o0);
    F[3] = (float)selV(V, 0, o1); F[4] = (float)selV(V, 1, o1); F[5] = (float)selV(V, 2, o1);
    F[6] = (float)selV(V, 0, o2); F[7] = (float)selV(V, 1, o2); F[8] = (float)selV(V, 2, o2);
    normals[(size_t)g * 3 + 0] = F[0];
    normals[(size_t)g * 3 + 1] = F[1];
    normals[(size_t)g * 3 + 2] = F[2];
}

// -------------------------------------- edge dot-signs (packed) + u16 ----
// code = sign(n0_j . n0_n)+1 in {0,1,2}; 16 codes per u32, packed via two
// ballots + 16-bit interleave on lanes 0..3 of each wave.
__global__ __launch_bounds__(256) void edgesign_kernel(const int* __restrict__ idx,
                                                       const float* __restrict__ normals,
                                                       unsigned* __restrict__ dsgnp,
                                                       unsigned short* __restrict__ idx16) {
    const int e = blockIdx.x * 256 + threadIdx.x;   // 0 .. B*N*K-1
    const int lane = threadIdx.x & 63;
    const int b = e / (NPTS * KNB);
    const int r = e - b * NPTS * KNB;
    const int n = r / KNB;
    const int j = idx[e];
    idx16[e] = (unsigned short)j;
    const float* NB = normals + (size_t)b * NPTS * 3;
    const float d = __fadd_rn(__fadd_rn(__fmul_rn(NB[j * 3 + 0], NB[n * 3 + 0]),
                                        __fmul_rn(NB[j * 3 + 1], NB[n * 3 + 1])),
                              __fmul_rn(NB[j * 3 + 2], NB[n * 3 + 2]));
    // code bit0 = (d==0), bit1 = (d>0)   => code = sign(d)+1
    const unsigned long long m0 = __ballot(d == 0.0f);
    const unsigned long long m1 = __ballot(d > 0.0f);
    if (lane < 4) {
        unsigned x = (unsigned)(m0 >> (lane * 16)) & 0xFFFFu;
        unsigned y = (unsigned)(m1 >> (lane * 16)) & 0xFFFFu;
        x = (x | (x << 8)) & 0x00FF00FFu; x = (x | (x << 4)) & 0x0F0F0F0Fu;
        x = (x | (x << 2)) & 0x33333333u; x = (x | (x << 1)) & 0x55555555u;
        y = (y | (y << 8)) & 0x00FF00FFu; y = (y | (y << 4)) & 0x0F0F0F0Fu;
        y = (y | (y << 2)) & 0x33333333u; y = (y | (y << 1)) & 0x55555555u;
        dsgnp[((e - lane) >> 4) + lane] = x | (y << 1);
    }
}

// ------------------------------------------------------------- BFS ----
// Frozen R0-proven structure (measured ~40.5us; 3 structural experiments
// regressed, 2 micro-experiments null => structural floor):
//  * round-tagged winners: val = ((round+1)<<17)|flat, monotone across
//    rounds => no winner reset; "touched this round" = (w >= tag).
//  * merged P2+P3 over double-buffered sg (reference reads pre-round
//    state): 2 barriers/round, one dense scalar pass (j = tid+u*1024).
//  * P1 = compact list, hoisted register staging (4 items/thread,
//    unrolled, independent loads), non-returning atomicMax. EL[] dedup
//    (owner-thread-only writes), ballot-aggregated list append.
__global__ __launch_bounds__(1024) void bfs_kernel(const unsigned short* __restrict__ idx16,
                                                   const unsigned* __restrict__ dsgnp,
                                                   float* __restrict__ nrm) {
    const int tid = threadIdx.x;
    const int lane = tid & 63;
    __shared__ int winner[BATCH * NPTS];                 // 32 KB
    __shared__ short sgbuf[2][BATCH * NPTS];             // 32 KB
    __shared__ unsigned dsp[NPACK];                      // 40 KB
    __shared__ unsigned short list[NPTS];                //  8 KB
    __shared__ short EL[NPTS];                           //  8 KB
    __shared__ int cntsh;

    for (int j = tid; j < NPTS; j += 1024) {
        winner[j] = 0; winner[NPTS + j] = 0;
        sgbuf[0][j] = 1; sgbuf[0][NPTS + j] = 1;
        EL[j] = 0;
    }
    for (int i = tid; i < NPACK; i += 1024) dsp[i] = dsgnp[i];   // coalesced
    if (tid == 0) { cntsh = 1; list[0] = 0; EL[0] = 1; }
    __syncthreads();

    int cur = 0;
    int rstart = 0, rend = 1;
    for (int round = 0; round < NROUNDS; ++round) {
        const int tag = (round + 1) << 17;
        // ---- P1: scatter winners (hoisted staging, 4 items/thread/chunk)
        const int items = (rend - rstart) * BATCH;
        for (int base = 0; base < items; base += 4096) {
            unsigned pr[4][KNB / 2];
            int tflat[4], wbase[4];
            bool ok[4];
#pragma unroll
            for (int s = 0; s < 4; ++s) {
                const int w = base + s * 1024 + tid;
                ok[s] = (w < items);
                if (ok[s]) {
                    const int i = w >> 1, b = w & 1;
                    const int n0 = (int)list[rstart + i];
                    tflat[s] = tag + n0 * KNB;
                    wbase[s] = b * NPTS;
                    const unsigned* rp =
                        (const unsigned*)(idx16 + ((size_t)b * NPTS + n0) * KNB);
#pragma unroll
                    for (int u = 0; u < KNB / 2; ++u) pr[s][u] = rp[u];
                }
            }
#pragma unroll
            for (int s = 0; s < 4; ++s) {
                if (ok[s]) {
#pragma unroll
                    for (int u = 0; u < KNB / 2; ++u) {
                        const int j0 = (int)(pr[s][u] & 0xffffu);
                        const int j1 = (int)(pr[s][u] >> 16);
                        atomicMax(&winner[wbase[s] + j0], tflat[s] + 2 * u);
                        atomicMax(&winner[wbase[s] + j1], tflat[s] + 2 * u + 1);
                    }
                }
            }
        }
        __syncthreads();
        // ---- merged P2+P3: dense pass, sg double-buffer, no winner reset
        const short* sgOld = sgbuf[cur];
        short* sgNew = sgbuf[cur ^ 1];
#pragma unroll
        for (int u = 0; u < 4; ++u) {
            const int j = tid + u * 1024;
            bool marked = false;
#pragma unroll
            for (int b = 0; b < BATCH; ++b) {
                const int bj = b * NPTS + j;
                const int w = winner[bj];
                short s = sgOld[bj];
                if (w >= tag) {
                    const int flat = w - tag;          // n*KNB + k
                    const int nsrc = flat / KNB;
                    const int wi = b * (NPTS * KNB) + flat;
                    const int d = (int)((dsp[wi >> 4] >> ((wi & 15) << 1)) & 3u) - 1;
                    const short sn = sgOld[b * NPTS + nsrc];
                    s = d ? (short)(d * sn) : (short)(-s);
                    if (flat % KNB != 0) marked = true;
                }
                sgNew[bj] = s;
            }
            const bool f = marked && !EL[j];
            if (f) EL[j] = 1;
            const unsigned long long mask = __ballot(f);
            if (mask) {
                const int lead = (int)(__ffsll((long long)mask) - 1);
                int basep = 0;
                if (lane == lead) basep = atomicAdd(&cntsh, (int)__popcll(mask));
                basep = __shfl(basep, lead, 64);
                if (f) list[basep + (int)__popcll(mask & ((1ull << lane) - 1ull))] =
                           (unsigned short)j;
            }
        }
        __syncthreads();
        cur ^= 1;
        rstart = rend;
        rend = cntsh;                 // uniform read after barrier
        if (rstart == rend) break;
    }
    // apply signs to normals in place (coalesced)
    const short* sgF = sgbuf[cur];
    for (int i = tid; i < BATCH * NPTS * 3; i += 1024) {
        if (sgF[i / 3] < 0) nrm[i] = -nrm[i];
    }
}

// ----------------------------------------- tangent, Voronoi area, gauss ----
__global__ __launch_bounds__(256) void geom_kernel(const float* __restrict__ pts,
                                                   const int* __restrict__ idx,
                                                   const float* __restrict__ frames,
                                                   const float* __restrict__ nrm,
                                                   double* __restrict__ pervals) {
    const int lane = threadIdx.x & 63;
    const int q = blockIdx.x * 4 + (threadIdx.x >> 6);   // b*NPTS + n
    const int b = q >> 12, n = q & (NPTS - 1);
    const float* P  = pts + (size_t)b * NPTS * 3;
    const float* NR = nrm + (size_t)b * NPTS * 3;
    const float* F  = frames + (size_t)q * 9;

    const float v0x = NR[n * 3 + 0], v0y = NR[n * 3 + 1], v0z = NR[n * 3 + 2];
    const float v1x = F[3], v1y = F[4], v1z = F[5];
    const float v2x = F[6], v2y = F[7], v2z = F[8];
    const float det = v0x * (v1y * v2z - v1z * v2y)
                    - v0y * (v1x * v2z - v1z * v2x)
                    + v0z * (v1x * v2y - v1y * v2x);
    const float t1x = v1x * det, t1y = v1y * det, t1z = v1z * det;
    const float t2x = v2x, t2y = v2y, t2z = v2z;

    const bool isk = lane < KNB;
    float ptx = 0.f, pty = 0.f, qtx = 0.f, qty = 0.f;
    if (isk) {
        const int j = idx[(size_t)q * KNB + lane];
        const float dx = P[j * 3 + 0] - P[n * 3 + 0];
        const float dy = P[j * 3 + 1] - P[n * 3 + 1];
        const float dz = P[j * 3 + 2] - P[n * 3 + 2];
        ptx = dx * t1x + dy * t1y + dz * t1z;
        pty = dx * t2x + dy * t2y + dz * t2z;
        const float ex = NR[j * 3 + 0] - v0x;
        const float ey = NR[j * 3 + 1] - v0y;
        const float ez = NR[j * 3 + 2] - v0z;
        qtx = ex * t1x + ey * t1y + ez * t1z;
        qty = ex * t2x + ey * t2y + ez * t2z;
    }

    float mnx = isk ? ptx :  3e38f, mny = isk ? pty :  3e38f;
    float mxx = isk ? ptx : -3e38f, mxy = isk ? pty : -3e38f;
#pragma unroll
    for (int off = 32; off; off >>= 1) {
        mnx = fminf(mnx, __shfl_xor(mnx, off, 64));
        mny = fminf(mny, __shfl_xor(mny, off, 64));
        mxx = fmaxf(mxx, __shfl_xor(mxx, off, 64));
        mxy = fmaxf(mxy, __shfl_xor(mxy, off, 64));
    }
    mnx *= 1.1f; mny *= 1.1f; mxx *= 1.1f; mxy *= 1.1f;
    const float ml = fmaxf(mxx - mnx, mxy - mny);

    const float cx = (ptx - mnx) / ml * 2.0f - 1.0f;
    const float cy = (pty - mny) / ml * 2.0f - 1.0f;
    const float c0x = __shfl(cx, 0, 64), c0y = __shfl(cy, 0, 64);

    const float ax = 2.0f * (cx - c0x);
    const float ay = 2.0f * (cy - c0y);
    const float bbk = cx * cx + cy * cy - (c0x * c0x + c0y * c0y);
    const float inva = (ay != 0.0f) ? (1.0f / ay) : 0.0f;

    const float gx = (float)(-1.0 + (2.0 * (double)lane) / 63.0);
    float lo = -3e38f, hi = 3e38f;
    bool feas = true;
#pragma unroll
    for (int k = 1; k < KNB; ++k) {
        const float axk = __shfl(ax, k, 64);
        const float ayk = __shfl(ay, k, 64);
        const float bk  = __shfl(bbk, k, 64);
        const float ik  = __shfl(inva, k, 64);
        const float rk  = bk - gx * axk;
        const float t   = rk * ik;
        if (ayk > 0.0f)      hi = fminf(hi, t);
        else if (ayk < 0.0f) lo = fmaxf(lo, t);
        else                 feas = feas && (rk >= 0.0f);
    }
    int cnt = 0;
    if (feas) {
        const float hif = fminf((hi + 1.0f) * 31.5f, 63.0f);
        const float lof = fmaxf((lo + 1.0f) * 31.5f, 0.0f);
        const int jhi = (int)floorf(hif);
        const int jlo = (int)ceilf(lof);
        cnt = jhi - jlo + 1;
        if (cnt < 0) cnt = 0;
    }
#pragma unroll
    for (int off = 32; off; off >>= 1) cnt += __shfl_xor(cnt, off, 64);
    const float area = (float)cnt * ml * ml / 3969.0f;   // (W-1)^2

    double xx00 = 0, xx01 = 0, xx11 = 0, yx00 = 0, yx01 = 0, yx10 = 0, yx11 = 0;
    if (isk) {
        const double px = ptx, py = pty, qx2 = qtx, qy2 = qty;
        xx00 = px * px; xx01 = px * py; xx11 = py * py;
        yx00 = qx2 * px; yx01 = qx2 * py; yx10 = qy2 * px; yx11 = qy2 * py;
    }
#pragma unroll
    for (int off = 32; off; off >>= 1) {
        xx00 += __shfl_xor(xx00, off, 64);
        xx01 += __shfl_xor(xx01, off, 64);
        xx11 += __shfl_xor(xx11, off, 64);
        yx00 += __shfl_xor(yx00, off, 64);
        yx01 += __shfl_xor(yx01, off, 64);
        yx10 += __shfl_xor(yx10, off, 64);
        yx11 += __shfl_xor(yx11, off, 64);
    }
    if (lane == 0) {
        const double m00 = xx00 + 1e-8, m01 = xx01, m11 = xx11 + 1e-8;
        const double dm = m00 * m11 - m01 * m01;
        const double i00 = m11 / dm, i01 = -m01 / dm, i11 = m00 / dm;
        const double w00 = yx00 * i00 + yx01 * i01;
        const double w01 = yx00 * i01 + yx01 * i11;
        const double w10 = yx10 * i00 + yx11 * i01;
        const double w11 = yx10 * i01 + yx11 * i11;
        const double off2 = 0.5 * (w01 + w10);
        const double gauss = w00 * w11 - off2 * off2;
        pervals[q] = gauss * (double)area;
    }
}

// ------------------------------------------------------------ reduce ----
__global__ __launch_bounds__(256) void reduce_kernel(const double* __restrict__ pervals,
                                                     float* __restrict__ out) {
    const int b = blockIdx.x, tid = threadIdx.x;
    __shared__ double sm[256];
    double s = 0.0;
    for (int i = tid; i < NPTS; i += 256) s += pervals[(size_t)b * NPTS + i];
    sm[tid] = s;
    __syncthreads();
    for (int st = 128; st > 0; st >>= 1) {
        if (tid < st) sm[tid] += sm[tid + st];
        __syncthreads();
    }
    if (tid == 0) out[b] = (float)(sm[0] / 3.14159265358979323846 / 2.0);
}

// ------------------------------------------------------------ launch ----
extern "C" void kernel_launch(void* const* d_in, const int* in_sizes, int n_in,
                              void* d_out, int out_size, void* d_ws, size_t ws_size,
                              hipStream_t stream) {
    (void)in_sizes; (void)n_in; (void)out_size; (void)ws_size;
    const float* pts = (const float*)d_in[0];
    char* ws = (char*)d_ws;

    size_t off = 0;
    double* pervals = (double*)(ws + off); off += (size_t)BATCH * NPTS * sizeof(double);
    int*    idx     = (int*)(ws + off);    off += (size_t)BATCH * NPTS * KNB * sizeof(int);
    float*  frames  = (float*)(ws + off);  off += (size_t)BATCH * NPTS * 9 * sizeof(float);
    float*  normals = (float*)(ws + off);  off += (size_t)BATCH * NPTS * 3 * sizeof(float);
    unsigned short* idx16 = (unsigned short*)(ws + off);
    off += (size_t)BATCH * NPTS * KNB * sizeof(unsigned short);
    unsigned* dsgnp = (unsigned*)(ws + off);
    off += (size_t)NPACK * sizeof(unsigned);

    knn_kernel<<<BATCH * NPTS / KQ, 1024, 0, stream>>>(pts, idx);
    frames_kernel<<<BATCH * NPTS / 64, 64, 0, stream>>>(pts, idx, frames, normals);
    edgesign_kernel<<<BATCH * NPTS * KNB / 256, 256, 0, stream>>>(idx, normals, dsgnp, idx16);
    bfs_kernel<<<1, 1024, 0, stream>>>(idx16, dsgnp, normals);
    geom_kernel<<<BATCH * NPTS / 4, 256, 0, stream>>>(pts, idx, frames, normals, pervals);
    reduce_kernel<<<BATCH, 256, 0, stream>>>(pervals, (float*)d_out);
}

// Round 12
// 99.381 us; speedup vs baseline: 1.0058x; 1.0058x over previous
//
#include <hip/hip_runtime.h>
#include <math.h>

#define NPTS  4096
#define BATCH 2
#define KNB   20
#define WGRID 64
#define GCELLS (WGRID * WGRID)
#define NROUNDS 32
#define KBUF  192
#define KQ    16                            // queries per kNN block (1 wave each)
#define NEDGE (BATCH * NPTS * KNB)          // 163840
#define NPACK (NEDGE / 16)                  // 10240 u32 (2-bit codes)

// ---------------------------------------------------------------- kNN ----
// R4-proven shape (~38us): 16 waves/block, 1 query/wave, batch staged once
// in LDS (w = |p|^2 computed during staging). Two-pass distance (no d[64]
// array) => VGPR <= 64 => 8 waves/SIMD, 2 blocks/CU (LDS 70KB) => 32
// waves/CU. Threshold rank-select via ballot radix-select (R9, zero
// DS-pipe traffic, exact same value as bitonic sorted[19]).
__device__ __forceinline__ float knn_dist(const float4 c, const float px,
                                          const float py, const float pz,
                                          const float sqn, const int m,
                                          const int n) {
    const float dot = px * c.x + py * c.y + pz * c.z;
    float dist = (sqn + c.w) - 2.0f * dot;
    if (m == n) dist = -1.0f;
    return dist;
}

__device__ __forceinline__ unsigned long long knn_key(const float dist, const int m) {
    unsigned u = __float_as_uint(dist);
    u = (dist < 0.0f) ? ~u : (u | 0x80000000u);
    return ((unsigned long long)u << 32) | (unsigned)m;
}

__global__ __launch_bounds__(1024, 8) void knn_kernel(const float* __restrict__ pts,
                                                      int* __restrict__ idx) {
    const int tid  = threadIdx.x;
    const int lane = tid & 63;
    const int wid  = tid >> 6;                      // 0..15
    const int q    = blockIdx.x * KQ + wid;         // 0 .. B*N-1
    const int b    = q >> 12;
    const int n    = q & (NPTS - 1);
    const float* P = pts + (size_t)b * NPTS * 3;

    __shared__ float4 spts[NPTS];                       // 64 KB
    __shared__ unsigned short buf[KQ][KBUF];            //  6 KB

    for (int i = tid; i < NPTS; i += 1024) {
        const float x = P[i * 3 + 0], y = P[i * 3 + 1], z = P[i * 3 + 2];
        spts[i] = make_float4(x, y, z, x * x + y * y + z * z);
    }
    __syncthreads();

    const float4 me = spts[n];
    const float px = me.x, py = me.y, pz = me.z, sqn = me.w;

    // ---- pass 1: per-lane min over its 64 points (no storage)
    float lmin = 3e38f;
#pragma unroll
    for (int step = 0; step < 64; ++step) {
        const int m = lane + step * 64;
        lmin = fminf(lmin, knn_dist(spts[m], px, py, pz, sqn, m, n));
    }

    // ---- threshold = 20th smallest of the 64 lane-mins, via ballot
    // radix-select on the monotone uint mapping (no shuffles; exact
    // same value as bitonic sorted[19], duplicates included).
    unsigned ub = __float_as_uint(lmin);
    ub = (lmin < 0.0f) ? ~ub : (ub | 0x80000000u);
    unsigned val = 0;
    int need = KNB;                  // 20 => 0-indexed rank 19
    bool alive = true;
#pragma unroll
    for (int bit = 31; bit >= 0; --bit) {
        const unsigned bm = 1u << bit;
        const unsigned long long z = __ballot(alive && !(ub & bm));
        const int c = __popcll(z);
        const bool pick1 = (c < need);
        if (pick1) { need -= c; val |= bm; }
        alive = alive && (((ub & bm) != 0) == pick1);
    }
    float tsel;
    if (val & 0x80000000u) tsel = __uint_as_float(val & 0x7fffffffu);
    else                   tsel = __uint_as_float(~val);
    float thr = tsel + fabsf(tsel) * 1e-4f + 1e-6f;

    // ---- pass 2: recompute distances, compact candidate indices (u16)
    unsigned short* wbuf = buf[wid];
    int cnt = 0;
#pragma unroll
    for (int step = 0; step < 64; ++step) {
        const int m = lane + step * 64;
        const float dist = knn_dist(spts[m], px, py, pz, sqn, m, n);
        const bool keep = (dist <= thr);
        const unsigned long long mask = __ballot(keep);
        if (keep) {
            const int pos = cnt + __popcll(mask & ((1ull << lane) - 1ull));
            if (pos < KBUF) wbuf[pos] = (unsigned short)m;
        }
        cnt += __popcll(mask);
    }

    const int M = (cnt < KBUF) ? cnt : KBUF;
    int* op = idx + (size_t)q * KNB;
    const unsigned long long MAXK = ~0ull;
    if (M <= 64) {
        unsigned long long key = MAXK;
        if (lane < M) {
            const int m = (int)wbuf[lane];
            key = knn_key(knn_dist(spts[m], px, py, pz, sqn, m, n), m);
        }
#pragma unroll
        for (int k = 2; k <= 64; k <<= 1) {
#pragma unroll
            for (int j = k >> 1; j >= 1; j >>= 1) {
                const unsigned long long o = __shfl_xor(key, j, 64);
                const bool up    = ((lane & k) == 0);
                const bool lower = ((lane & j) == 0);
                const bool takeMin = (lower == up);
                const unsigned long long mn = key < o ? key : o;
                const unsigned long long mx = key < o ? o : key;
                key = takeMin ? mn : mx;
            }
        }
        if (lane < KNB) op[lane] = (int)(unsigned)(key & 0xffffffffu);
    } else {
        unsigned long long s0 = MAXK, s1 = MAXK, s2 = MAXK;
        if (lane < M) {
            const int m = (int)wbuf[lane];
            s0 = knn_key(knn_dist(spts[m], px, py, pz, sqn, m, n), m);
        }
        if (lane + 64 < M) {
            const int m = (int)wbuf[lane + 64];
            s1 = knn_key(knn_dist(spts[m], px, py, pz, sqn, m, n), m);
        }
        if (lane + 128 < M) {
            const int m = (int)wbuf[lane + 128];
            s2 = knn_key(knn_dist(spts[m], px, py, pz, sqn, m, n), m);
        }
#pragma unroll 1
        for (int r = 0; r < KNB; ++r) {
            unsigned long long kk = s0 < s1 ? s0 : s1;
            kk = kk < s2 ? kk : s2;
#pragma unroll
            for (int off = 32; off; off >>= 1) {
                const unsigned long long ok = __shfl_xor(kk, off, 64);
                kk = ok < kk ? ok : kk;
            }
            if (s0 == kk) s0 = MAXK;
            else if (s1 == kk) s1 = MAXK;
            else if (s2 == kk) s2 = MAXK;
            if (lane == 0) op[r] = (int)(unsigned)(kk & 0xffffffffu);
        }
    }
}

// ------------------------------------------------------- frames (eigh) ----
template <int p, int q, int r>
__device__ __forceinline__ void jrot(double A[3][3], double V[3][3]) {
    double apq = A[p][q];
    if (fabs(apq) < 1e-300) return;
    double app = A[p][p], aqq = A[q][q];
    double tau = (aqq - app) / (2.0 * apq);
    double sq  = sqrt(1.0 + tau * tau);
    double t   = (tau >= 0.0) ? (1.0 / (tau + sq)) : (1.0 / (tau - sq));
    double c   = 1.0 / sqrt(1.0 + t * t);
    double s   = t * c;
    A[p][p] = app - t * apq; A[q][q] = aqq + t * apq;
    A[p][q] = 0.0; A[q][p] = 0.0;
    double arp = A[r][p], arq = A[r][q];
    A[r][p] = c * arp - s * arq; A[p][r] = A[r][p];
    A[r][q] = s * arp + c * arq; A[q][r] = A[r][q];
#pragma unroll
    for (int i = 0; i < 3; ++i) {
        double vip = V[i][p], viq = V[i][q];
        V[i][p] = c * vip - s * viq;
        V[i][q] = s * vip + c * viq;
    }
}

__device__ __forceinline__ double selV(const double V[3][3], int i, int c) {
    return c == 0 ? V[i][0] : (c == 1 ? V[i][1] : V[i][2]);
}

__global__ __launch_bounds__(64) void frames_kernel(const float* __restrict__ pts,
                                                    const int* __restrict__ idx,
                                                    float* __restrict__ frames,
                                                    float* __restrict__ normals) {
    const int g = blockIdx.x * 64 + threadIdx.x;    // 0 .. B*N-1
    const int b = g / NPTS;
    const float* P  = pts + (size_t)b * NPTS * 3;
    const int*   ip = idx + (size_t)g * KNB;

    float mx = 0.f, my = 0.f, mz = 0.f;
#pragma unroll
    for (int k = 0; k < KNB; ++k) {
        const int j = ip[k];
        mx += P[j * 3 + 0]; my += P[j * 3 + 1]; mz += P[j * 3 + 2];
    }
    mx /= 20.0f; my /= 20.0f; mz /= 20.0f;

    float c00 = 0.f, c01 = 0.f, c02 = 0.f, c11 = 0.f, c12 = 0.f, c22 = 0.f;
#pragma unroll
    for (int k = 0; k < KNB; ++k) {
        const int j = ip[k];
        const float x = P[j * 3 + 0] - mx;
        const float y = P[j * 3 + 1] - my;
        const float z = P[j * 3 + 2] - mz;
        c00 += x * x; c01 += x * y; c02 += x * z;
        c11 += y * y; c12 += y * z; c22 += z * z;
    }
    c00 *= 0.5f; c01 *= 0.5f; c02 *= 0.5f; c11 *= 0.5f; c12 *= 0.5f; c22 *= 0.5f;

    double A[3][3] = {{c00, c01, c02}, {c01, c11, c12}, {c02, c12, c22}};
    double V[3][3] = {{1, 0, 0}, {0, 1, 0}, {0, 0, 1}};
#pragma unroll
    for (int sw = 0; sw < 10; ++sw) {
        jrot<0, 1, 2>(A, V);
        jrot<0, 2, 1>(A, V);
        jrot<1, 2, 0>(A, V);
    }
    double e0 = A[0][0], e1 = A[1][1], e2 = A[2][2];
    int o0 = 0, o1 = 1, o2 = 2;
    if (e0 > e1) { double t = e0; e0 = e1; e1 = t; int o = o0; o0 = o1; o1 = o; }
    if (e1 > e2) { double t = e1; e1 = e2; e2 = t; int o = o1; o1 = o2; o2 = o; }
    if (e0 > e1) { double t = e0; e0 = e1; e1 = t; int o = o0; o0 = o1; o1 = o; }

    float* F = frames + (size_t)g * 9;
    F[0] = (float)selV(V, 0, o0); F[1] = (float)selV(V, 1, o0); F[2] = (float)selV(V, 2, o0);
    F[3] = (float)selV(V, 0, o1); F[4] = (float)selV(V, 1, o1); F[5] = (float)selV(V, 2, o1);
    F[6] = (float)selV(V, 0, o2); F[7] = (float)selV(V, 1, o2); F[8] = (float)selV(V, 2, o2);
    normals[(size_t)g * 3 + 0] = F[0];
    normals[(size_t)g * 3 + 1] = F[1];
    normals[(size_t)g * 3 + 2] = F[2];
}

// -------------------------------------- edge dot-signs (packed) + u16 ----
// code = sign(n0_j . n0_n)+1 in {0,1,2}; 16 codes per u32, packed via two
// ballots + 16-bit interleave on lanes 0..3 of each wave.
__global__ __launch_bounds__(256) void edgesign_kernel(const int* __restrict__ idx,
                                                       const float* __restrict__ normals,
                                                       unsigned* __restrict__ dsgnp,
                                                       unsigned short* __restrict__ idx16) {
    const int e = blockIdx.x * 256 + threadIdx.x;   // 0 .. B*N*K-1
    const int lane = threadIdx.x & 63;
    const int b = e / (NPTS * KNB);
    const int r = e - b * NPTS * KNB;
    const int n = r / KNB;
    const int j = idx[e];
    idx16[e] = (unsigned short)j;
    const float* NB = normals + (size_t)b * NPTS * 3;
    const float d = __fadd_rn(__fadd_rn(__fmul_rn(NB[j * 3 + 0], NB[n * 3 + 0]),
                                        __fmul_rn(NB[j * 3 + 1], NB[n * 3 + 1])),
                              __fmul_rn(NB[j * 3 + 2], NB[n * 3 + 2]));
    // code bit0 = (d==0), bit1 = (d>0)   => code = sign(d)+1
    const unsigned long long m0 = __ballot(d == 0.0f);
    const unsigned long long m1 = __ballot(d > 0.0f);
    if (lane < 4) {
        unsigned x = (unsigned)(m0 >> (lane * 16)) & 0xFFFFu;
        unsigned y = (unsigned)(m1 >> (lane * 16)) & 0xFFFFu;
        x = (x | (x << 8)) & 0x00FF00FFu; x = (x | (x << 4)) & 0x0F0F0F0Fu;
        x = (x | (x << 2)) & 0x33333333u; x = (x | (x << 1)) & 0x55555555u;
        y = (y | (y << 8)) & 0x00FF00FFu; y = (y | (y << 4)) & 0x0F0F0F0Fu;
        y = (y | (y << 2)) & 0x33333333u; y = (y | (y << 1)) & 0x55555555u;
        dsgnp[((e - lane) >> 4) + lane] = x | (y << 1);
    }
}

// ------------------------------------------------------------- BFS ----
// Frozen R0-proven structure (measured ~40.5us; 3 structural experiments
// regressed, 2 micro-experiments null => structural floor):
//  * round-tagged winners: val = ((round+1)<<17)|flat, monotone across
//    rounds => no winner reset; "touched this round" = (w >= tag).
//  * merged P2+P3 over double-buffered sg (reference reads pre-round
//    state): 2 barriers/round, one dense scalar pass (j = tid+u*1024).
//  * P1 = compact list, hoisted register staging (4 items/thread,
//    unrolled, independent loads), non-returning atomicMax. EL[] dedup
//    (owner-thread-only writes), ballot-aggregated list append.
__global__ __launch_bounds__(1024) void bfs_kernel(const unsigned short* __restrict__ idx16,
                                                   const unsigned* __restrict__ dsgnp,
                                                   float* __restrict__ nrm) {
    const int tid = threadIdx.x;
    const int lane = tid & 63;
    __shared__ int winner[BATCH * NPTS];                 // 32 KB
    __shared__ short sgbuf[2][BATCH * NPTS];             // 32 KB
    __shared__ unsigned dsp[NPACK];                      // 40 KB
    __shared__ unsigned short list[NPTS];                //  8 KB
    __shared__ short EL[NPTS];                           //  8 KB
    __shared__ int cntsh;

    for (int j = tid; j < NPTS; j += 1024) {
        winner[j] = 0; winner[NPTS + j] = 0;
        sgbuf[0][j] = 1; sgbuf[0][NPTS + j] = 1;
        EL[j] = 0;
    }
    for (int i = tid; i < NPACK; i += 1024) dsp[i] = dsgnp[i];   // coalesced
    if (tid == 0) { cntsh = 1; list[0] = 0; EL[0] = 1; }
    __syncthreads();

    int cur = 0;
    int rstart = 0, rend = 1;
    for (int round = 0; round < NROUNDS; ++round) {
        const int tag = (round + 1) << 17;
        // ---- P1: scatter winners (hoisted staging, 4 items/thread/chunk)
        const int items = (rend - rstart) * BATCH;
        for (int base = 0; base < items; base += 4096) {
            unsigned pr[4][KNB / 2];
            int tflat[4], wbase[4];
            bool ok[4];
#pragma unroll
            for (int s = 0; s < 4; ++s) {
                const int w = base + s * 1024 + tid;
                ok[s] = (w < items);
                if (ok[s]) {
                    const int i = w >> 1, b = w & 1;
                    const int n0 = (int)list[rstart + i];
                    tflat[s] = tag + n0 * KNB;
                    wbase[s] = b * NPTS;
                    const unsigned* rp =
                        (const unsigned*)(idx16 + ((size_t)b * NPTS + n0) * KNB);
#pragma unroll
                    for (int u = 0; u < KNB / 2; ++u) pr[s][u] = rp[u];
                }
            }
#pragma unroll
            for (int s = 0; s < 4; ++s) {
                if (ok[s]) {
#pragma unroll
                    for (int u = 0; u < KNB / 2; ++u) {
                        const int j0 = (int)(pr[s][u] & 0xffffu);
                        const int j1 = (int)(pr[s][u] >> 16);
                        atomicMax(&winner[wbase[s] + j0], tflat[s] + 2 * u);
                        atomicMax(&winner[wbase[s] + j1], tflat[s] + 2 * u + 1);
                    }
                }
            }
        }
        __syncthreads();
        // ---- merged P2+P3: dense pass, sg double-buffer, no winner reset
        const short* sgOld = sgbuf[cur];
        short* sgNew = sgbuf[cur ^ 1];
#pragma unroll
        for (int u = 0; u < 4; ++u) {
            const int j = tid + u * 1024;
            bool marked = false;
#pragma unroll
            for (int b = 0; b < BATCH; ++b) {
                const int bj = b * NPTS + j;
                const int w = winner[bj];
                short s = sgOld[bj];
                if (w >= tag) {
                    const int flat = w - tag;          // n*KNB + k
                    const int nsrc = flat / KNB;
                    const int wi = b * (NPTS * KNB) + flat;
                    const int d = (int)((dsp[wi >> 4] >> ((wi & 15) << 1)) & 3u) - 1;
                    const short sn = sgOld[b * NPTS + nsrc];
                    s = d ? (short)(d * sn) : (short)(-s);
                    if (flat % KNB != 0) marked = true;
                }
                sgNew[bj] = s;
            }
            const bool f = marked && !EL[j];
            if (f) EL[j] = 1;
            const unsigned long long mask = __ballot(f);
            if (mask) {
                const int lead = (int)(__ffsll((long long)mask) - 1);
                int basep = 0;
                if (lane == lead) basep = atomicAdd(&cntsh, (int)__popcll(mask));
                basep = __shfl(basep, lead, 64);
                if (f) list[basep + (int)__popcll(mask & ((1ull << lane) - 1ull))] =
                           (unsigned short)j;
            }
        }
        __syncthreads();
        cur ^= 1;
        rstart = rend;
        rend = cntsh;                 // uniform read after barrier
        if (rstart == rend) break;
    }
    // apply signs to normals in place (coalesced)
    const short* sgF = sgbuf[cur];
    for (int i = tid; i < BATCH * NPTS * 3; i += 1024) {
        if (sgF[i / 3] < 0) nrm[i] = -nrm[i];
    }
}

// ----------------------------------------- tangent, Voronoi area, gauss ----
__global__ __launch_bounds__(256) void geom_kernel(const float* __restrict__ pts,
                                                   const int* __restrict__ idx,
                                                   const float* __restrict__ frames,
                                                   const float* __restrict__ nrm,
                                                   double* __restrict__ pervals) {
    const int lane = threadIdx.x & 63;
    const int q = blockIdx.x * 4 + (threadIdx.x >> 6);   // b*NPTS + n
    const int b = q >> 12, n = q & (NPTS - 1);
    const float* P  = pts + (size_t)b * NPTS * 3;
    const float* NR = nrm + (size_t)b * NPTS * 3;
    const float* F  = frames + (size_t)q * 9;

    const float v0x = NR[n * 3 + 0], v0y = NR[n * 3 + 1], v0z = NR[n * 3 + 2];
    const float v1x = F[3], v1y = F[4], v1z = F[5];
    const float v2x = F[6], v2y = F[7], v2z = F[8];
    const float det = v0x * (v1y * v2z - v1z * v2y)
                    - v0y * (v1x * v2z - v1z * v2x)
                    + v0z * (v1x * v2y - v1y * v2x);
    const float t1x = v1x * det, t1y = v1y * det, t1z = v1z * det;
    const float t2x = v2x, t2y = v2y, t2z = v2z;

    const bool isk = lane < KNB;
    float ptx = 0.f, pty = 0.f, qtx = 0.f, qty = 0.f;
    if (isk) {
        const int j = idx[(size_t)q * KNB + lane];
        const float dx = P[j * 3 + 0] - P[n * 3 + 0];
        const float dy = P[j * 3 + 1] - P[n * 3 + 1];
        const float dz = P[j * 3 + 2] - P[n * 3 + 2];
        ptx = dx * t1x + dy * t1y + dz * t1z;
        pty = dx * t2x + dy * t2y + dz * t2z;
        const float ex = NR[j * 3 + 0] - v0x;
        const float ey = NR[j * 3 + 1] - v0y;
        const float ez = NR[j * 3 + 2] - v0z;
        qtx = ex * t1x + ey * t1y + ez * t1z;
        qty = ex * t2x + ey * t2y + ez * t2z;
    }

    float mnx = isk ? ptx :  3e38f, mny = isk ? pty :  3e38f;
    float mxx = isk ? ptx : -3e38f, mxy = isk ? pty : -3e38f;
#pragma unroll
    for (int off = 32; off; off >>= 1) {
        mnx = fminf(mnx, __shfl_xor(mnx, off, 64));
        mny = fminf(mny, __shfl_xor(mny, off, 64));
        mxx = fmaxf(mxx, __shfl_xor(mxx, off, 64));
        mxy = fmaxf(mxy, __shfl_xor(mxy, off, 64));
    }
    mnx *= 1.1f; mny *= 1.1f; mxx *= 1.1f; mxy *= 1.1f;
    const float ml = fmaxf(mxx - mnx, mxy - mny);

    const float cx = (ptx - mnx) / ml * 2.0f - 1.0f;
    const float cy = (pty - mny) / ml * 2.0f - 1.0f;
    const float c0x = __shfl(cx, 0, 64), c0y = __shfl(cy, 0, 64);

    const float ax = 2.0f * (cx - c0x);
    const float ay = 2.0f * (cy - c0y);
    const float bbk = cx * cx + cy * cy - (c0x * c0x + c0y * c0y);
    const float inva = (ay != 0.0f) ? (1.0f / ay) : 0.0f;

    const float gx = (float)(-1.0 + (2.0 * (double)lane) / 63.0);
    float lo = -3e38f, hi = 3e38f;
    bool feas = true;
#pragma unroll
    for (int k = 1; k < KNB; ++k) {
        const float axk = __shfl(ax, k, 64);
        const float ayk = __shfl(ay, k, 64);
        const float bk  = __shfl(bbk, k, 64);
        const float ik  = __shfl(inva, k, 64);
        const float rk  = bk - gx * axk;
        const float t   = rk * ik;
        if (ayk > 0.0f)      hi = fminf(hi, t);
        else if (ayk < 0.0f) lo = fmaxf(lo, t);
        else                 feas = feas && (rk >= 0.0f);
    }
    int cnt = 0;
    if (feas) {
        const float hif = fminf((hi + 1.0f) * 31.5f, 63.0f);
        const float lof = fmaxf((lo + 1.0f) * 31.5f, 0.0f);
        const int jhi = (int)floorf(hif);
        const int jlo = (int)ceilf(lof);
        cnt = jhi - jlo + 1;
        if (cnt < 0) cnt = 0;
    }
#pragma unroll
    for (int off = 32; off; off >>= 1) cnt += __shfl_xor(cnt, off, 64);
    const float area = (float)cnt * ml * ml / 3969.0f;   // (W-1)^2

    double xx00 = 0, xx01 = 0, xx11 = 0, yx00 = 0, yx01 = 0, yx10 = 0, yx11 = 0;
    if (isk) {
        const double px = ptx, py = pty, qx2 = qtx, qy2 = qty;
        xx00 = px * px; xx01 = px * py; xx11 = py * py;
        yx00 = qx2 * px; yx01 = qx2 * py; yx10 = qy2 * px; yx11 = qy2 * py;
    }
#pragma unroll
    for (int off = 32; off; off >>= 1) {
        xx00 += __shfl_xor(xx00, off, 64);
        xx01 += __shfl_xor(xx01, off, 64);
        xx11 += __shfl_xor(xx11, off, 64);
        yx00 += __shfl_xor(yx00, off, 64);
        yx01 += __shfl_xor(yx01, off, 64);
        yx10 += __shfl_xor(yx10, off, 64);
        yx11 += __shfl_xor(yx11, off, 64);
    }
    if (lane == 0) {
        const double m00 = xx00 + 1e-8, m01 = xx01, m11 = xx11 + 1e-8;
        const double dm = m00 * m11 - m01 * m01;
        const double i00 = m11 / dm, i01 = -m01 / dm, i11 = m00 / dm;
        const double w00 = yx00 * i00 + yx01 * i01;
        const double w01 = yx00 * i01 + yx01 * i11;
        const double w10 = yx10 * i00 + yx11 * i01;
        const double w11 = yx10 * i01 + yx11 * i11;
        const double off2 = 0.5 * (w01 + w10);
        const double gauss = w00 * w11 - off2 * off2;
        pervals[q] = gauss * (double)area;
    }
}

// ------------------------------------------------------------ reduce ----
__global__ __launch_bounds__(256) void reduce_kernel(const double* __restrict__ pervals,
                                                     float* __restrict__ out) {
    const int b = blockIdx.x, tid = threadIdx.x;
    __shared__ double sm[256];
    double s = 0.0;
    for (int i = tid; i < NPTS; i += 256) s += pervals[(size_t)b * NPTS + i];
    sm[tid] = s;
    __syncthreads();
    for (int st = 128; st > 0; st >>= 1) {
        if (tid < st) sm[tid] += sm[tid + st];
        __syncthreads();
    }
    if (tid == 0) out[b] = (float)(sm[0] / 3.14159265358979323846 / 2.0);
}

// ------------------------------------------------------------ launch ----
extern "C" void kernel_launch(void* const* d_in, const int* in_sizes, int n_in,
                              void* d_out, int out_size, void* d_ws, size_t ws_size,
                              hipStream_t stream) {
    (void)in_sizes; (void)n_in; (void)out_size; (void)ws_size;
    const float* pts = (const float*)d_in[0];
    char* ws = (char*)d_ws;

    size_t off = 0;
    double* pervals = (double*)(ws + off); off += (size_t)BATCH * NPTS * sizeof(double);
    int*    idx     = (int*)(ws + off);    off += (size_t)BATCH * NPTS * KNB * sizeof(int);
    float*  frames  = (float*)(ws + off);  off += (size_t)BATCH * NPTS * 9 * sizeof(float);
    float*  normals = (float*)(ws + off);  off += (size_t)BATCH * NPTS * 3 * sizeof(float);
    unsigned short* idx16 = (unsigned short*)(ws + off);
    off += (size_t)BATCH * NPTS * KNB * sizeof(unsigned short);
    unsigned* dsgnp = (unsigned*)(ws + off);
    off += (size_t)NPACK * sizeof(unsigned);

    knn_kernel<<<BATCH * NPTS / KQ, 1024, 0, stream>>>(pts, idx);
    frames_kernel<<<BATCH * NPTS / 64, 64, 0, stream>>>(pts, idx, frames, normals);
    edgesign_kernel<<<BATCH * NPTS * KNB / 256, 256, 0, stream>>>(idx, normals, dsgnp, idx16);
    bfs_kernel<<<1, 1024, 0, stream>>>(idx16, dsgnp, normals);
    geom_kernel<<<BATCH * NPTS / 4, 256, 0, stream>>>(pts, idx, frames, normals, pervals);
    reduce_kernel<<<BATCH, 256, 0, stream>>>(pervals, (float*)d_out);
}